// Round 5
// baseline (1351.187 us; speedup 1.0000x reference)
//
#include <hip/hip_runtime.h>

typedef unsigned short u16;
typedef unsigned int u32;
typedef __attribute__((ext_vector_type(8))) __bf16 bf16x8;
typedef __attribute__((ext_vector_type(4))) float f32x4;
typedef __attribute__((ext_vector_type(16))) float f32x16;
typedef __attribute__((ext_vector_type(4))) u32 u32x4;
typedef __attribute__((ext_vector_type(4))) u16 u16x4;

#define T_SEQ 4096
#define DM 1024

__device__ __forceinline__ u16 f2bf(float f) {
  u32 u = __builtin_bit_cast(u32, f);
  u = (u + 0x7fffu + ((u >> 16) & 1u)) >> 16;
  return (u16)u;
}

__device__ __forceinline__ void gll16(const void* g, void* l) {
  __builtin_amdgcn_global_load_lds(
      (const __attribute__((address_space(1))) u32*)g,
      (__attribute__((address_space(3))) u32*)l, 16, 0, 0);
}

__device__ __forceinline__ bf16x8 lds_frag(const void* p) {
  return __builtin_bit_cast(bf16x8, *(const u32x4*)p);
}

// ---------------------------------------------------------------------------
// Kernel 1: fp32 -> bf16 conversion of x and Wq/Wk/Wv
// ---------------------------------------------------------------------------
__global__ __launch_bounds__(256) void cvt_kernel(
    const float* __restrict__ x, const float* __restrict__ wq,
    const float* __restrict__ wk, const float* __restrict__ wv,
    u16* __restrict__ Xb, u16* __restrict__ Wb) {
  const int NX = 4194304;  // x float4 units (16M floats)
  const int NW = 262144;   // per-W float4 units (1M floats)
  const int total = NX + 3 * NW;
  for (int i = blockIdx.x * 256 + threadIdx.x; i < total;
       i += gridDim.x * 256) {
    const float* src;
    u16* dst;
    if (i < NX) {
      src = x + (size_t)i * 4;
      dst = Xb + (size_t)i * 4;
    } else {
      const int j = i - NX;
      const int seg = j >> 18;  // 0,1,2
      const int o = j & (NW - 1);
      const float* wsel = seg == 0 ? wq : (seg == 1 ? wk : wv);
      src = wsel + (size_t)o * 4;
      dst = Wb + (size_t)j * 4;
    }
    const f32x4 v = *(const f32x4*)src;
    u16x4 r;
    r[0] = f2bf(v[0]); r[1] = f2bf(v[1]); r[2] = f2bf(v[2]); r[3] = f2bf(v[3]);
    *(u16x4*)dst = r;
  }
}

// ---------------------------------------------------------------------------
// Kernel 2: fused QKV projection GEMM (bf16 MFMA)
//   C[m][n] = sum_k X[m][k] * W[n][k],  M=16384, N=3072 (Q|K|V), K=1024
//   Q,K written row-major bf16 [b*T+t][d]; V written transposed [b*D+d][t]
// ---------------------------------------------------------------------------
__global__ __launch_bounds__(256, 2) void qkv_gemm(
    const u16* __restrict__ Xb, const u16* __restrict__ Wb,
    u16* __restrict__ Qg, u16* __restrict__ Kg, u16* __restrict__ Vt) {
  __shared__ alignas(16) u16 As[128 * 64];
  __shared__ alignas(16) u16 Bs[128 * 64];
  const int tid = threadIdx.x;
  const int lane = tid & 63, w = tid >> 6;
  const int wm = w >> 1, wn = w & 1;
  const int l4 = lane >> 4, lr = lane & 15;
  const int bm = blockIdx.x & 127, bn = blockIdx.x >> 7;
  const int mbase = bm * 128, nbase = bn * 128;

  f32x4 acc[4][4];
#pragma unroll
  for (int i = 0; i < 4; ++i)
#pragma unroll
    for (int j = 0; j < 4; ++j) acc[i][j] = (f32x4){0.f, 0.f, 0.f, 0.f};

  for (int kt = 0; kt < 16; ++kt) {
    __syncthreads();
#pragma unroll
    for (int i = 0; i < 4; ++i) {
      const int idx = w * 4 + i;              // 0..15, 1KB each
      const int row = idx * 8 + (lane >> 3);  // 0..127
      const int cb = (lane & 7) * 16;         // byte within 128B row
      const int cbs = cb ^ ((row & 7) << 4);  // pre-swizzled source
      gll16(Xb + (size_t)(mbase + row) * 1024 + kt * 64 + (cbs >> 1),
            (char*)As + idx * 1024);
      gll16(Wb + (size_t)(nbase + row) * 1024 + kt * 64 + (cbs >> 1),
            (char*)Bs + idx * 1024);
    }
    __syncthreads();
#pragma unroll
    for (int kk = 0; kk < 2; ++kk) {
      bf16x8 af[4], bfv[4];
#pragma unroll
      for (int mi = 0; mi < 4; ++mi) {
        const int row = wm * 64 + mi * 16 + lr;
        const int cb = (kk * 64 + l4 * 16) ^ ((row & 7) << 4);
        af[mi] = lds_frag((const char*)As + row * 128 + cb);
      }
#pragma unroll
      for (int ni = 0; ni < 4; ++ni) {
        const int row = wn * 64 + ni * 16 + lr;
        const int cb = (kk * 64 + l4 * 16) ^ ((row & 7) << 4);
        bfv[ni] = lds_frag((const char*)Bs + row * 128 + cb);
      }
#pragma unroll
      for (int mi = 0; mi < 4; ++mi)
#pragma unroll
        for (int ni = 0; ni < 4; ++ni)
          acc[mi][ni] = __builtin_amdgcn_mfma_f32_16x16x32_bf16(
              af[mi], bfv[ni], acc[mi][ni], 0, 0, 0);
    }
  }

  // epilogue: C row = token m (row=(l>>4)*4+j), col = output-dim n (col=l&15)
#pragma unroll
  for (int mi = 0; mi < 4; ++mi) {
#pragma unroll
    for (int ni = 0; ni < 4; ++ni) {
      const int n = nbase + wn * 64 + ni * 16 + lr;
      const int seg = n >> 10, d = n & 1023;
      const int m0 = mbase + wm * 64 + mi * 16 + l4 * 4;
      if (seg < 2) {
        u16* dst = seg ? Kg : Qg;
#pragma unroll
        for (int j = 0; j < 4; ++j)
          dst[(size_t)(m0 + j) * 1024 + d] = f2bf(acc[mi][ni][j]);
      } else {
        const int bb = m0 >> 12, t = m0 & 4095;  // 4 consecutive t, same b
        u16x4 pk;
#pragma unroll
        for (int j = 0; j < 4; ++j) pk[j] = f2bf(acc[mi][ni][j]);
        *(u16x4*)(Vt + ((size_t)bb * 1024 + d) * 4096 + t) = pk;
      }
    }
  }
}

// ---------------------------------------------------------------------------
// Kernel 3: flash attention, causal, head-dim 1024
//   block = (batch, 32 q-rows), 8 waves (512 thr), KV tile 64
//   QK^T: 32x32x16 MFMA, wave=(frag f, k-slice s), partials summed by LDS
//         atomicAdd into 8KB Ss (halves QK^T LDS fragment traffic)
//   K: double-buffered LDS chunks (256 dims), counted vmcnt + raw barriers
//   V: direct global->register reads, triple-buffered, hoisted under softmax
// ---------------------------------------------------------------------------
__global__ __launch_bounds__(512, 2) void attn_kernel(
    const u16* __restrict__ Qg, const u16* __restrict__ Kg,
    const u16* __restrict__ Vtg, float* __restrict__ Og) {
  __shared__ alignas(16) u16 Qs[32 * 1024];    // 64KB, row 2048B, swizzled
  __shared__ alignas(16) u16 Ks[2][64 * 256];  // 2x32KB, row 512B, swizzled
  __shared__ alignas(16) float Ss2[2 * 1024];  // 8KB: [frag][32r x 32c]
  __shared__ alignas(16) u16 Ps[32 * 64];      // 4KB, row 128B, swizzled
  __shared__ alignas(16) float rS[32];
  __shared__ alignas(16) float lS[32];

  const int tid = threadIdx.x;
  const int lane = tid & 63;
  const int w = tid >> 6;      // 0..7
  const int l4 = lane >> 4;    // 0..3
  const int lr = lane & 15;
  const int r_own = tid >> 4;  // softmax row 0..31
  const int cgrp = tid & 15;   // softmax col-group

  // XCD-partitioned mapping: b fixed per XCD pair; heavy q-tiles first.
  const int bx = blockIdx.x;
  const int b = (bx >> 1) & 3;
  const int qt_raw = ((bx >> 3) << 1) | (bx & 1);
  const int qt = (T_SEQ / 32 - 1) - qt_raw;  // 127..0, heavy first
  const int qbase = qt * 32;

  const u16* Qb = Qg + ((size_t)b * T_SEQ + qbase) * DM;
  const u16* Kb = Kg + (size_t)b * T_SEQ * DM;
  const u16* Vb = Vtg + (size_t)b * DM * T_SEQ;
  float* Ob = Og + ((size_t)b * T_SEQ + qbase) * DM;

  // stage Q [32][1024] (8 gll16 per wave)
#pragma unroll
  for (int i = 0; i < 8; ++i) {
    const int idx = w * 8 + i;  // 0..63, 1KB each (half a 2048B row)
    const int row = idx >> 1;
    const int cb = (idx & 1) * 1024 + lane * 16;
    const int cbs = cb ^ ((row & 7) << 4);
    gll16(Qb + (size_t)row * DM + (cbs >> 1), (char*)Qs + idx * 1024);
  }

  const int nkt = (qbase + 32 + 63) >> 6;

  // prologue: stage K chunk (kt=0, c=0) -> Ks[0]
#pragma unroll
  for (int i = 0; i < 4; ++i) {
    const int idx = w * 4 + i;              // 0..31
    const int row = idx * 2 + (lane >> 5);  // 0..63
    const int cb = (lane & 31) * 16;
    const int cbs = cb ^ ((row & 7) << 4);
    gll16(Kb + (size_t)row * DM + (cbs >> 1), (char*)Ks[0] + idx * 1024);
  }

  f32x4 acc[2][8];
#pragma unroll
  for (int mi = 0; mi < 2; ++mi)
#pragma unroll
    for (int n = 0; n < 8; ++n) acc[mi][n] = (f32x4){0.f, 0.f, 0.f, 0.f};

  float mrow = -1e30f, lrow = 0.f;
  // QK^T wave role: frag fgl (S cols fgl*32..+32), k-slice sQ (64 d per chunk)
  const int fgl = w >> 2;
  const int sQ = w & 3;
  const int rowA = lane & 31;             // q row for A fragment
  const int hi8 = (lane >> 5) * 16;       // byte offset of k-half in frag
  const int swA = (rowA & 7) << 4;
  const int rowB = fgl * 32 + (lane & 31);  // t_k row for B fragment
  const int swB = (rowB & 7) << 4;

  for (int kt = 0; kt < nkt; ++kt) {
    // zero Ss partial-sum buffer (barriers inside c-loop order this vs adds)
    ((f32x4*)Ss2)[tid] = (f32x4){0.f, 0.f, 0.f, 0.f};

    // ---------------- QK^T: 4 chunks of 256 dims, K double-buffered -------
    f32x16 sf0 = {0.f, 0.f, 0.f, 0.f, 0.f, 0.f, 0.f, 0.f,
                  0.f, 0.f, 0.f, 0.f, 0.f, 0.f, 0.f, 0.f};
    f32x16 sf1 = {0.f, 0.f, 0.f, 0.f, 0.f, 0.f, 0.f, 0.f,
                  0.f, 0.f, 0.f, 0.f, 0.f, 0.f, 0.f, 0.f};
#pragma unroll
    for (int c = 0; c < 4; ++c) {
      const int nc = (c < 3) ? c + 1 : 0;
      const int nk = (c < 3) ? kt : kt + 1;
      if (nk < nkt) {
        u16* dst = Ks[(c + 1) & 1];
#pragma unroll
        for (int i = 0; i < 4; ++i) {
          const int idx = w * 4 + i;              // 0..31
          const int row = idx * 2 + (lane >> 5);  // 0..63
          const int cb = (lane & 31) * 16;
          const int cbs = cb ^ ((row & 7) << 4);
          gll16(Kb + (size_t)(nk * 64 + row) * DM + nc * 256 + (cbs >> 1),
                (char*)dst + idx * 1024);
        }
        asm volatile("s_waitcnt vmcnt(4)" ::: "memory");
      } else {
        asm volatile("s_waitcnt vmcnt(0)" ::: "memory");
      }
      __builtin_amdgcn_s_barrier();  // chunk c landed everywhere
      const char* ksrc = (const char*)Ks[c & 1];
      const char* qrow_l = (const char*)Qs + rowA * 2048;
      const char* krow_l = ksrc + rowB * 512;
      __builtin_amdgcn_s_setprio(1);
#pragma unroll
      for (int km = 0; km < 4; km += 2) {
        const int base = sQ * 128 + km * 32 + hi8;
        const bf16x8 a0 = lds_frag(qrow_l + ((c * 512 + base) ^ swA));
        const bf16x8 b0 = lds_frag(krow_l + (base ^ swB));
        sf0 = __builtin_amdgcn_mfma_f32_32x32x16_bf16(a0, b0, sf0, 0, 0, 0);
        const bf16x8 a1 = lds_frag(qrow_l + ((c * 512 + base + 32) ^ swA));
        const bf16x8 b1 = lds_frag(krow_l + ((base + 32) ^ swB));
        sf1 = __builtin_amdgcn_mfma_f32_32x32x16_bf16(a1, b1, sf1, 0, 0, 0);
      }
      __builtin_amdgcn_s_setprio(0);
      asm volatile("s_waitcnt lgkmcnt(0)" ::: "memory");
      __builtin_amdgcn_s_barrier();  // reads of slot done -> re-stageable
    }
    // accumulate k-slice partial into Ss2 (C/D: col=l&31, row=(r&3)+8(r>>2)+4hi)
    {
      const f32x16 sfm = sf0 + sf1;
      float* sdst = &Ss2[fgl * 1024 + (lane & 31)];
      const int rhi = (lane >> 5) * 4;
#pragma unroll
      for (int r = 0; r < 16; ++r) {
        const int row = (r & 3) + 8 * (r >> 2) + rhi;
        atomicAdd(sdst + row * 32, sfm[r]);
      }
    }
    asm volatile("s_waitcnt lgkmcnt(0)" ::: "memory");
    __builtin_amdgcn_s_barrier();

    // ---------------- V prefetch (chunks 0,1) + online softmax ------------
#define LOADV(VV, C2)                                                         \
  {                                                                           \
    _Pragma("unroll") for (int nn = 0; nn < 2; ++nn) {                        \
      const u16* vp = Vb +                                                    \
          (size_t)((C2) * 256 + nn * 128 + w * 16 + lr) * 4096 + kt * 64 +    \
          l4 * 8;                                                             \
      VV[nn][0] = *(const bf16x8*)vp;                                         \
      VV[nn][1] = *(const bf16x8*)(vp + 32);                                  \
    }                                                                         \
  }
#define PVMFMA(VV, C2)                                                        \
  {                                                                           \
    __builtin_amdgcn_s_setprio(1);                                            \
    _Pragma("unroll") for (int nn = 0; nn < 2; ++nn)                          \
        _Pragma("unroll") for (int kk = 0; kk < 2; ++kk)                      \
            _Pragma("unroll") for (int mi = 0; mi < 2; ++mi)                  \
                acc[mi][(C2) * 2 + nn] =                                      \
        __builtin_amdgcn_mfma_f32_16x16x32_bf16(                              \
            pf[mi][kk], VV[nn][kk], acc[mi][(C2) * 2 + nn], 0, 0, 0);         \
    __builtin_amdgcn_s_setprio(0);                                            \
  }

    bf16x8 va[2][2], vb[2][2], vc[2][2];
    LOADV(va, 0);  // V latency hides under softmax VALU below
    LOADV(vb, 1);

    {
      // t_k local col = cgrp*4+j -> frag = cgrp>>3, col-in-frag = (cgrp&7)*4
      const f32x4 s4 =
          *(const f32x4*)&Ss2[(cgrp >> 3) * 1024 + r_own * 32 + (cgrp & 7) * 4];
      const int colbase = kt * 64 + cgrp * 4;
      const int qrow = qbase + r_own;
      float s0 = s4[0] * 0.03125f; if (colbase + 0 > qrow) s0 = -1e30f;
      float s1 = s4[1] * 0.03125f; if (colbase + 1 > qrow) s1 = -1e30f;
      float s2 = s4[2] * 0.03125f; if (colbase + 2 > qrow) s2 = -1e30f;
      float s3 = s4[3] * 0.03125f; if (colbase + 3 > qrow) s3 = -1e30f;
      float tm = fmaxf(fmaxf(s0, s1), fmaxf(s2, s3));
#pragma unroll
      for (int m = 1; m < 16; m <<= 1) tm = fmaxf(tm, __shfl_xor(tm, m));
      const float newm = fmaxf(mrow, tm);
      const float rsc = __expf(mrow - newm);
      const float p0 = __expf(s0 - newm);
      const float p1 = __expf(s1 - newm);
      const float p2 = __expf(s2 - newm);
      const float p3 = __expf(s3 - newm);
      float psum = (p0 + p1) + (p2 + p3);
#pragma unroll
      for (int m = 1; m < 16; m <<= 1) psum += __shfl_xor(psum, m);
      lrow = lrow * rsc + psum;
      mrow = newm;
      u16x4 pu;
      pu[0] = f2bf(p0); pu[1] = f2bf(p1); pu[2] = f2bf(p2); pu[3] = f2bf(p3);
      *(u16x4*)((char*)Ps + r_own * 128 + ((cgrp * 8) ^ ((r_own & 7) << 4))) = pu;
      if (cgrp == 0) rS[r_own] = rsc;
    }
    asm volatile("s_waitcnt lgkmcnt(0)" ::: "memory");
    __builtin_amdgcn_s_barrier();

    // ---------------- PV: V direct from global, no barriers ---------------
    LOADV(vc, 2);  // chunk 2 in flight before first PV MFMA

    // rescale O accumulator (VALU)
#pragma unroll
    for (int mi = 0; mi < 2; ++mi) {
#pragma unroll
      for (int j = 0; j < 4; ++j) {
        const float f = rS[mi * 16 + l4 * 4 + j];
#pragma unroll
        for (int n = 0; n < 8; ++n) acc[mi][n][j] *= f;
      }
    }
    // hoist P fragments (reused across all 4 d-chunks)
    bf16x8 pf[2][2];
#pragma unroll
    for (int mi = 0; mi < 2; ++mi)
#pragma unroll
      for (int kk = 0; kk < 2; ++kk) {
        const int rowp = mi * 16 + lr;
        const int xp = kk * 64 + l4 * 16;
        pf[mi][kk] =
            lds_frag((const char*)Ps + rowp * 128 + (xp ^ ((lr & 7) << 4)));
      }

    PVMFMA(va, 0);
    LOADV(va, 3);  // chunk 3 hides under PV clusters 1,2
    PVMFMA(vb, 1);
    PVMFMA(vc, 2);
    PVMFMA(va, 3);
#undef LOADV
#undef PVMFMA
  }

  if (cgrp == 0) lS[r_own] = lrow;
  asm volatile("s_waitcnt lgkmcnt(0)" ::: "memory");
  __builtin_amdgcn_s_barrier();

  float linv[2][4];
#pragma unroll
  for (int mi = 0; mi < 2; ++mi)
#pragma unroll
    for (int j = 0; j < 4; ++j) linv[mi][j] = 1.0f / lS[mi * 16 + l4 * 4 + j];

#pragma unroll
  for (int mi = 0; mi < 2; ++mi)
#pragma unroll
    for (int n = 0; n < 8; ++n) {
      const int dcol = (n >> 1) * 256 + (n & 1) * 128 + w * 16 + lr;
#pragma unroll
      for (int j = 0; j < 4; ++j) {
        const int trow = mi * 16 + l4 * 4 + j;
        Ob[(size_t)trow * DM + dcol] = acc[mi][n][j] * linv[mi][j];
      }
    }
}

// ---------------------------------------------------------------------------
extern "C" void kernel_launch(void* const* d_in, const int* in_sizes, int n_in,
                              void* d_out, int out_size, void* d_ws,
                              size_t ws_size, hipStream_t stream) {
  (void)in_sizes; (void)n_in; (void)out_size; (void)ws_size;
  const float* x = (const float*)d_in[0];
  const float* Wq = (const float*)d_in[1];
  const float* Wk = (const float*)d_in[2];
  const float* Wv = (const float*)d_in[3];

  u16* Xb = (u16*)d_ws;                     // 16M elems (32MB)
  u16* Wb = Xb + (size_t)16 * 1024 * 1024;  // 3M elems  (6MB)
  u16* Qg = Wb + (size_t)3 * 1024 * 1024;   // 16M elems (32MB)
  u16* Kg = Qg + (size_t)16 * 1024 * 1024;  // 16M elems (32MB)
  u16* Vt = Kg + (size_t)16 * 1024 * 1024;  // 16M elems, transposed [b*D+d][t]

  cvt_kernel<<<2048, 256, 0, stream>>>(x, Wq, Wk, Wv, Xb, Wb);
  qkv_gemm<<<128 * 24, 256, 0, stream>>>(Xb, Wb, Qg, Kg, Vt);
  attn_kernel<<<512, 512, 0, stream>>>(Qg, Kg, Vt, (float*)d_out);
}